// Round 1
// baseline (155098.022 us; speedup 1.0000x reference)
//
#include <hip/hip_runtime.h>
#include <hip/hip_bf16.h>

// BiLSTM-CRF on MI355X.
// Sizes (fixed per reference): VOCAB=50000, EMB=256, HID=512 (H=256/dir),
// NTAG=20, SEQ=8192.
//
// Pipeline:
//  1) xg_project : xg[d][t][r] = (bih+bhh)[r] + sum_e embed[sent[t]][e]*Wih_d[r][e]
//  2) lstm_scan  : 2 persistent blocks (one per direction), Whh in VGPRs,
//                  h broadcast via LDS, writes lstm_out[t][0:256]=h_f, [256:512]=h_b
//  3) emissions  : em[t][j] = bout[j] + lstm_out[t][:] . Wout[j][:]
//  4) viterbi_fwd: sequential max-plus scan (1 wave), bp bytes to ws
//  5) bt_maps / bt_boundary / bt_emit : chunked parallel backtrace
//     (backpointer rows compose associatively: tag_{t-1} = bp[t][tag_t])

#define S    8192
#define E    256
#define Hh   256          // per-direction hidden
#define G    1024         // 4*Hh gates
#define NT   20
#define NCHUNK 128        // 8192 / 64
#define CLEN   64

// ---------------------------------------------------------------- xg projection
__global__ __launch_bounds__(256, 4) void xg_project(
    const int* __restrict__ sent, const float* __restrict__ embed,
    const float* __restrict__ Wih_f, const float* __restrict__ bih_f, const float* __restrict__ bhh_f,
    const float* __restrict__ Wih_b, const float* __restrict__ bih_b, const float* __restrict__ bhh_b,
    float* __restrict__ xg)                       // [2][S][G]
{
    const int tb  = blockIdx.x;                   // 0..255 (32 timesteps each)
    const int rb  = blockIdx.y;                   // 0..3
    const int dir = blockIdx.z;                   // 0..1
    const int tid = threadIdx.x;
    const int r   = rb * 256 + tid;               // gate row 0..1023
    const float* Wih = dir ? Wih_b : Wih_f;

    __shared__ __align__(16) float4 xs4[32 * 64]; // 32 timesteps x 256 floats

    const int t0 = tb * 32;
    // stage gathered embedding rows (coalesced float4)
    #pragma unroll
    for (int i = 0; i < 8; ++i) {
        int q   = i * 256 + tid;
        int row = q >> 6;                          // 64 float4 per row
        int c4  = q & 63;
        int idx = sent[t0 + row];
        xs4[q] = *(const float4*)(embed + (size_t)idx * E + (size_t)c4 * 4);
    }

    // weight row into registers (256 VGPRs)
    float w[E];
    #pragma unroll
    for (int k = 0; k < E; k += 4) {
        float4 v = *(const float4*)(Wih + (size_t)r * E + k);
        w[k] = v.x; w[k+1] = v.y; w[k+2] = v.z; w[k+3] = v.w;
    }
    float bias = dir ? (bih_b[r] + bhh_b[r]) : (bih_f[r] + bhh_f[r]);
    __syncthreads();

    const float* xs = (const float*)xs4;
    float* outb = xg + ((size_t)dir * S + t0) * G + r;
    for (int tt = 0; tt < 32; ++tt) {
        float a0 = 0.f, a1 = 0.f, a2 = 0.f, a3 = 0.f;
        #pragma unroll
        for (int k = 0; k < E; k += 4) {
            float4 h4 = *(const float4*)(xs + tt * E + k);   // LDS broadcast
            a0 = fmaf(w[k],   h4.x, a0);
            a1 = fmaf(w[k+1], h4.y, a1);
            a2 = fmaf(w[k+2], h4.z, a2);
            a3 = fmaf(w[k+3], h4.w, a3);
        }
        outb[(size_t)tt * G] = bias + ((a0 + a1) + (a2 + a3));
    }
}

// ---------------------------------------------------------------- LSTM scan
// One block per direction. Thread r owns gate row r (Whh[r][:] in 256 VGPRs).
// Threads r<256 additionally own cell state c[r].
__global__ __launch_bounds__(1024, 4) void lstm_scan(
    const float* __restrict__ xg,                 // [2][S][G]
    const float* __restrict__ Whh_f,
    const float* __restrict__ Whh_b,
    float* __restrict__ out)                      // [S][512]
{
    const int dir = blockIdx.x;
    const int r   = threadIdx.x;
    const float* W   = dir ? Whh_b : Whh_f;
    const float* xgd = xg + (size_t)dir * S * G;

    float w[Hh];
    #pragma unroll
    for (int k = 0; k < Hh; k += 4) {
        float4 v = *(const float4*)(W + (size_t)r * Hh + k);
        w[k] = v.x; w[k+1] = v.y; w[k+2] = v.z; w[k+3] = v.w;
    }

    __shared__ __align__(16) float h_lds[Hh];
    __shared__ __align__(16) float gates[G];
    float c = 0.f;
    if (r < Hh) h_lds[r] = 0.f;

    const int t0 = dir ? (S - 1) : 0;
    const int dt = dir ? -1 : 1;
    float xg_cur = xgd[(size_t)t0 * G + r];

    float  h_keep = 0.f;                          // deferred global store
    size_t st_off = 0;
    __syncthreads();

    for (int s = 0; s < S; ++s) {
        const int t = t0 + dt * s;

        // deferred h store from previous step (overlaps matvec; drained at bar#1)
        if (s > 0 && r < Hh) out[st_off] = h_keep;

        // prefetch next step's xg (consumed after bar#2; hidden under matvec)
        float xg_next = 0.f;
        if (s + 1 < S) xg_next = xgd[(size_t)(t + dt) * G + r];

        // recurrent matvec: acc = xg + Whh[r][:] . h
        float a0 = xg_cur, a1 = 0.f, a2 = 0.f, a3 = 0.f;
        #pragma unroll
        for (int k = 0; k < Hh; k += 4) {
            float4 h4 = *(const float4*)(h_lds + k);         // LDS broadcast
            a0 = fmaf(w[k],   h4.x, a0);
            a1 = fmaf(w[k+1], h4.y, a1);
            a2 = fmaf(w[k+2], h4.z, a2);
            a3 = fmaf(w[k+3], h4.w, a3);
        }
        float acc = (a0 + a1) + (a2 + a3);

        // activation (wave-uniform branch: i,f,o sigmoid; g tanh)
        float a;
        if (r < 2 * Hh || r >= 3 * Hh) a = 1.f / (1.f + expf(-acc));
        else                           a = tanhf(acc);
        gates[r] = a;
        __syncthreads();                                     // bar#1

        if (r < Hh) {
            float iv = gates[r];
            float fv = gates[Hh + r];
            float gv = gates[2 * Hh + r];
            float ov = gates[3 * Hh + r];
            c = fv * c + iv * gv;
            float h = ov * tanhf(c);
            h_lds[r] = h;
            h_keep = h;
            st_off = (size_t)t * 512 + (size_t)dir * Hh + r;
        }
        __syncthreads();                                     // bar#2
        xg_cur = xg_next;
    }
    if (r < Hh) out[st_off] = h_keep;                        // final store
}

// ---------------------------------------------------------------- emissions
__global__ __launch_bounds__(256) void emissions_kernel(
    const float* __restrict__ lo,                 // [S][512]
    const float* __restrict__ Wout,               // [NT][512]
    const float* __restrict__ bout,
    float* __restrict__ em)                       // [S][NT]
{
    int gid = blockIdx.x * blockDim.x + threadIdx.x;
    if (gid >= S * NT) return;
    int t = gid / NT;
    int j = gid - t * NT;
    const float* x = lo + (size_t)t * 512;
    const float* w = Wout + (size_t)j * 512;
    float a0 = 0.f, a1 = 0.f, a2 = 0.f, a3 = 0.f;
    #pragma unroll 8
    for (int k = 0; k < 512; k += 4) {
        float4 xv = *(const float4*)(x + k);
        float4 wv = *(const float4*)(w + k);
        a0 = fmaf(xv.x, wv.x, a0);
        a1 = fmaf(xv.y, wv.y, a1);
        a2 = fmaf(xv.z, wv.z, a2);
        a3 = fmaf(xv.w, wv.w, a3);
    }
    em[gid] = bout[j] + ((a0 + a1) + (a2 + a3));
}

// ---------------------------------------------------------------- viterbi forward
__global__ __launch_bounds__(64) void viterbi_fwd(
    const float* __restrict__ em,                 // [S][NT]
    const float* __restrict__ start_trans,
    const float* __restrict__ end_trans,
    const float* __restrict__ trans,              // [NT][NT] (from,to)
    unsigned char* __restrict__ bp,               // [S][NT]
    int* __restrict__ last_out)
{
    const int j = threadIdx.x;
    const bool act = (j < NT);
    __shared__ __align__(16) float sc[2][NT];

    float tc[NT];                                 // trans column j
    if (act) {
        #pragma unroll
        for (int i = 0; i < NT; ++i) tc[i] = trans[i * NT + j];
        sc[0][j] = start_trans[j] + em[j];
        bp[j] = (unsigned char)j;                 // t=0: identity (never used on path)
    }
    __syncthreads();

    float e_cur = act ? em[NT + j] : 0.f;         // t=1 emission
    for (int t = 1; t < S; ++t) {
        float e_nxt = (act && t + 1 < S) ? em[(size_t)(t + 1) * NT + j] : 0.f;

        const float* sp = sc[(t - 1) & 1];
        float s0[NT];
        #pragma unroll
        for (int i = 0; i < NT; i += 4) {
            float4 v = *(const float4*)(sp + i);  // LDS broadcast
            s0[i] = v.x; s0[i+1] = v.y; s0[i+2] = v.z; s0[i+3] = v.w;
        }
        float bestv = s0[0] + tc[0];
        int   besti = 0;
        #pragma unroll
        for (int i = 1; i < NT; ++i) {
            float v = s0[i] + tc[i];
            if (v > bestv) { bestv = v; besti = i; }   // strict > : first-index ties (jnp.argmax)
        }
        if (act) {
            sc[t & 1][j] = bestv + e_cur;
            bp[(size_t)t * NT + j] = (unsigned char)besti;
        }
        __syncthreads();
        e_cur = e_nxt;
    }

    if (j == 0) {
        const float* sp = sc[(S - 1) & 1];
        float bv = sp[0] + end_trans[0];
        int   bi = 0;
        for (int i = 1; i < NT; ++i) {
            float v = sp[i] + end_trans[i];
            if (v > bv) { bv = v; bi = i; }
        }
        *last_out = bi;
    }
}

// ---------------------------------------------------------------- backtrace
// tag_{t-1} = bp[t][tag_t].  Chunk c covers t in [c*64, c*64+63].
// M_c[j] = result of applying bp[c*64+63] ... bp[c*64] starting from j
//        = tag at (c*64 - 1) given tag j at (c*64 + 63).
__global__ __launch_bounds__(64) void bt_maps(
    const unsigned char* __restrict__ bp, unsigned char* __restrict__ maps)
{
    __shared__ unsigned char lbp[CLEN * NT];      // 1280 B
    const int c = blockIdx.x, tid = threadIdx.x;
    const unsigned* src = (const unsigned*)(bp + (size_t)c * CLEN * NT);
    unsigned* dst = (unsigned*)lbp;
    for (int q = tid; q < CLEN * NT / 4; q += 64) dst[q] = src[q];
    __syncthreads();
    if (tid < NT) {
        int x = tid;
        for (int t = CLEN - 1; t >= 0; --t) x = lbp[t * NT + x];
        maps[c * NT + tid] = (unsigned char)x;
    }
}

__global__ __launch_bounds__(64) void bt_boundary(
    const unsigned char* __restrict__ maps, const int* __restrict__ last_out,
    int* __restrict__ btags)                      // btags[c] = tag at t = c*64+63
{
    __shared__ unsigned char m[NCHUNK * NT];
    const int tid = threadIdx.x;
    for (int q = tid; q < NCHUNK * NT; q += 64) m[q] = maps[q];
    __syncthreads();
    if (tid == 0) {
        int x = *last_out;
        btags[NCHUNK - 1] = x;
        for (int c = NCHUNK - 1; c >= 1; --c) {
            x = m[c * NT + x];
            btags[c - 1] = x;
        }
    }
}

__global__ __launch_bounds__(64) void bt_emit(
    const unsigned char* __restrict__ bp, const int* __restrict__ btags,
    int* __restrict__ path)
{
    __shared__ unsigned char lbp[CLEN * NT];
    const int c = blockIdx.x, tid = threadIdx.x;
    const unsigned* src = (const unsigned*)(bp + (size_t)c * CLEN * NT);
    unsigned* dst = (unsigned*)lbp;
    for (int q = tid; q < CLEN * NT / 4; q += 64) dst[q] = src[q];
    __syncthreads();
    if (tid == 0) {
        int x = btags[c];
        path[c * CLEN + CLEN - 1] = x;
        for (int t = CLEN - 1; t >= 1; --t) {
            x = lbp[t * NT + x];
            path[c * CLEN + t - 1] = x;
        }
    }
}

// ---------------------------------------------------------------- launcher
extern "C" void kernel_launch(void* const* d_in, const int* in_sizes, int n_in,
                              void* d_out, int out_size, void* d_ws, size_t ws_size,
                              hipStream_t stream) {
    const int*   sent   = (const int*)  d_in[0];
    const float* embed  = (const float*)d_in[1];
    const float* Wih_f  = (const float*)d_in[2];
    const float* Whh_f  = (const float*)d_in[3];
    const float* bih_f  = (const float*)d_in[4];
    const float* bhh_f  = (const float*)d_in[5];
    const float* Wih_b  = (const float*)d_in[6];
    const float* Whh_b  = (const float*)d_in[7];
    const float* bih_b  = (const float*)d_in[8];
    const float* bhh_b  = (const float*)d_in[9];
    const float* Wout   = (const float*)d_in[10];
    const float* bout   = (const float*)d_in[11];
    const float* start_trans = (const float*)d_in[12];
    const float* end_trans   = (const float*)d_in[13];
    const float* trans       = (const float*)d_in[14];
    int* path = (int*)d_out;

    char* ws = (char*)d_ws;
    size_t off = 0;
    float* xg = (float*)(ws + off); off += (size_t)2 * S * G * 4;   // 64 MB
    float* lo = (float*)(ws + off); off += (size_t)S * 512 * 4;     // 16 MB
    float* em = (float*)(ws + off); off += (size_t)S * NT * 4;      // 640 KB
    unsigned char* bp   = (unsigned char*)(ws + off); off += (size_t)S * NT;  // 160 KB
    unsigned char* maps = (unsigned char*)(ws + off); off += 4096;
    int* btags = (int*)(ws + off); off += 1024;
    int* lastp = (int*)(ws + off); off += 256;

    xg_project<<<dim3(S / 32, 4, 2), 256, 0, stream>>>(
        sent, embed, Wih_f, bih_f, bhh_f, Wih_b, bih_b, bhh_b, xg);
    lstm_scan<<<dim3(2), 1024, 0, stream>>>(xg, Whh_f, Whh_b, lo);
    emissions_kernel<<<dim3((S * NT + 255) / 256), 256, 0, stream>>>(lo, Wout, bout, em);
    viterbi_fwd<<<dim3(1), 64, 0, stream>>>(em, start_trans, end_trans, trans, bp, lastp);
    bt_maps<<<dim3(NCHUNK), 64, 0, stream>>>(bp, maps);
    bt_boundary<<<dim3(1), 64, 0, stream>>>(maps, lastp, btags);
    bt_emit<<<dim3(NCHUNK), 64, 0, stream>>>(bp, btags, path);
}

// Round 2
// 37541.223 us; speedup vs baseline: 4.1314x; 4.1314x over previous
//
#include <hip/hip_runtime.h>
#include <hip/hip_bf16.h>

// BiLSTM-CRF on MI355X.
// Sizes (fixed per reference): VOCAB=50000, EMB=256, HID=512 (H=256/dir),
// NTAG=20, SEQ=8192.
//
// Round-2 change: lstm_scan split across 4 CUs per direction (register-
// resident Whh needs 1 MB/dir; one CU has a 512 KB register file). Blocks
// synchronize once per timestep via agent-scope (LLC) atomics: h values are
// stored straight into lstm_out with sc1, a per-block flag is released, all
// blocks poll the 4 flags, then reload the full 256-float h into LDS.

#define S    8192
#define E    256
#define Hh   256          // per-direction hidden
#define G    1024         // 4*Hh gates
#define NT   20
#define NB   4            // blocks (CUs) per direction
#define NCHUNK 128        // 8192 / 64
#define CLEN   64

// ---------------------------------------------------------------- xg projection
// Identical arithmetic order to round 1 (bit-identical xg); only the
// launch bounds changed (256,4 capped VGPR at 128 and spilled w[256]).
__global__ __launch_bounds__(256, 1) void xg_project(
    const int* __restrict__ sent, const float* __restrict__ embed,
    const float* __restrict__ Wih_f, const float* __restrict__ bih_f, const float* __restrict__ bhh_f,
    const float* __restrict__ Wih_b, const float* __restrict__ bih_b, const float* __restrict__ bhh_b,
    float* __restrict__ xg)                       // [2][S][G]
{
    const int tb  = blockIdx.x;                   // 0..255 (32 timesteps each)
    const int rb  = blockIdx.y;                   // 0..3
    const int dir = blockIdx.z;                   // 0..1
    const int tid = threadIdx.x;
    const int r   = rb * 256 + tid;               // gate row 0..1023
    const float* Wih = dir ? Wih_b : Wih_f;

    __shared__ __align__(16) float4 xs4[32 * 64]; // 32 timesteps x 256 floats

    const int t0 = tb * 32;
    #pragma unroll
    for (int i = 0; i < 8; ++i) {
        int q   = i * 256 + tid;
        int row = q >> 6;                          // 64 float4 per row
        int c4  = q & 63;
        int idx = sent[t0 + row];
        xs4[q] = *(const float4*)(embed + (size_t)idx * E + (size_t)c4 * 4);
    }

    float w[E];
    #pragma unroll
    for (int k = 0; k < E; k += 4) {
        float4 v = *(const float4*)(Wih + (size_t)r * E + k);
        w[k] = v.x; w[k+1] = v.y; w[k+2] = v.z; w[k+3] = v.w;
    }
    float bias = dir ? (bih_b[r] + bhh_b[r]) : (bih_f[r] + bhh_f[r]);
    __syncthreads();

    const float* xs = (const float*)xs4;
    float* outb = xg + ((size_t)dir * S + t0) * G + r;
    for (int tt = 0; tt < 32; ++tt) {
        float a0 = 0.f, a1 = 0.f, a2 = 0.f, a3 = 0.f;
        #pragma unroll
        for (int k = 0; k < E; k += 4) {
            float4 h4 = *(const float4*)(xs + tt * E + k);   // LDS broadcast
            a0 = fmaf(w[k],   h4.x, a0);
            a1 = fmaf(w[k+1], h4.y, a1);
            a2 = fmaf(w[k+2], h4.z, a2);
            a3 = fmaf(w[k+3], h4.w, a3);
        }
        outb[(size_t)tt * G] = bias + ((a0 + a1) + (a2 + a3));
    }
}

// ---------------------------------------------------------------- flag init
__global__ __launch_bounds__(64) void init_flags(int* __restrict__ flags)
{
    if (threadIdx.x < 2 * NB)
        __hip_atomic_store(&flags[threadIdx.x], 0,
                           __ATOMIC_RELAXED, __HIP_MEMORY_SCOPE_AGENT);
}

// ---------------------------------------------------------------- LSTM scan
// Grid (NB, 2). Block (b,dir) owns h indices [b*64, b*64+64): 256 gate rows.
// Thread tid: gate = tid>>6 (i,f,g,o), hloc = tid&63; holds Whh[row][0:256]
// in 256 VGPRs. Per step: matvec from LDS-broadcast h, gate exchange via LDS,
// wave 0 updates c and stores h to lstm_out with agent scope (sc1 -> LLC),
// release flag, all blocks poll 4 flags, reload h from LLC into LDS.
__global__ __launch_bounds__(256, 1) void lstm_scan_mc(
    const float* __restrict__ xg,                 // [2][S][G]
    const float* __restrict__ Whh_f,
    const float* __restrict__ Whh_b,
    float* __restrict__ out,                      // [S][512]
    int* __restrict__ flags)                      // [2][NB]
{
    const int b    = blockIdx.x;
    const int dir  = blockIdx.y;
    const int tid  = threadIdx.x;
    const int gate = tid >> 6;
    const int hloc = tid & 63;
    const int hbase = b * 64;
    const int hidx  = hbase + hloc;
    const int row   = gate * Hh + hidx;
    const float* W   = dir ? Whh_b : Whh_f;
    const float* xgd = xg + (size_t)dir * S * G;
    int* flg = flags + dir * NB;

    float w[Hh];
    #pragma unroll
    for (int k = 0; k < Hh; k += 4) {
        float4 v = *(const float4*)(W + (size_t)row * Hh + k);
        w[k] = v.x; w[k+1] = v.y; w[k+2] = v.z; w[k+3] = v.w;
    }

    __shared__ __align__(16) float h_lds[Hh];
    __shared__ float gates_lds[256];
    h_lds[tid] = 0.f;
    float c = 0.f;

    const int t0 = dir ? (S - 1) : 0;
    const int dt = dir ? -1 : 1;
    float xg_cur = xgd[(size_t)t0 * G + row];
    __syncthreads();

    for (int s = 0; s < S; ++s) {
        const int t = t0 + dt * s;
        float xg_next = 0.f;
        if (s + 1 < S) xg_next = xgd[(size_t)(t + dt) * G + row];

        // matvec: acc = xg + Whh[row][:] . h   (h via wave-uniform LDS broadcast)
        float a0 = xg_cur, a1 = 0.f, a2 = 0.f, a3 = 0.f;
        #pragma unroll
        for (int k = 0; k < Hh; k += 4) {
            float4 h4 = *(const float4*)(h_lds + k);
            a0 = fmaf(w[k],   h4.x, a0);
            a1 = fmaf(w[k+1], h4.y, a1);
            a2 = fmaf(w[k+2], h4.z, a2);
            a3 = fmaf(w[k+3], h4.w, a3);
        }
        float acc = (a0 + a1) + (a2 + a3);
        float a = (gate == 2) ? tanhf(acc) : 1.f / (1.f + expf(-acc));
        gates_lds[tid] = a;
        __syncthreads();                                     // gates ready

        if (tid < 64) {                                      // wave 0: cell update
            float iv = gates_lds[hloc];
            float fv = gates_lds[64 + hloc];
            float gv = gates_lds[128 + hloc];
            float ov = gates_lds[192 + hloc];
            c = fv * c + iv * gv;
            float h = ov * tanhf(c);
            // sc1 store: bypasses XCD L2, lands at the LLC coherence point
            __hip_atomic_store(out + (size_t)t * 512 + dir * Hh + hidx, h,
                               __ATOMIC_RELAXED, __HIP_MEMORY_SCOPE_AGENT);
        }
        if (tid == 0)                                        // release: waits vmcnt(0)
            __hip_atomic_store(&flg[b], s + 1,
                               __ATOMIC_RELEASE, __HIP_MEMORY_SCOPE_AGENT);
        if (tid < NB)                                        // one poller per peer
            while (__hip_atomic_load(&flg[tid], __ATOMIC_RELAXED,
                                     __HIP_MEMORY_SCOPE_AGENT) < s + 1) {}
        __syncthreads();                                     // all peers done

        if (s + 1 < S)
            h_lds[tid] = __hip_atomic_load(out + (size_t)t * 512 + dir * Hh + tid,
                                           __ATOMIC_RELAXED, __HIP_MEMORY_SCOPE_AGENT);
        __syncthreads();
        xg_cur = xg_next;
    }
}

// ---------------------------------------------------------------- emissions
__global__ __launch_bounds__(256) void emissions_kernel(
    const float* __restrict__ lo,                 // [S][512]
    const float* __restrict__ Wout,               // [NT][512]
    const float* __restrict__ bout,
    float* __restrict__ em)                       // [S][NT]
{
    int gid = blockIdx.x * blockDim.x + threadIdx.x;
    if (gid >= S * NT) return;
    int t = gid / NT;
    int j = gid - t * NT;
    const float* x = lo + (size_t)t * 512;
    const float* w = Wout + (size_t)j * 512;
    float a0 = 0.f, a1 = 0.f, a2 = 0.f, a3 = 0.f;
    #pragma unroll 8
    for (int k = 0; k < 512; k += 4) {
        float4 xv = *(const float4*)(x + k);
        float4 wv = *(const float4*)(w + k);
        a0 = fmaf(xv.x, wv.x, a0);
        a1 = fmaf(xv.y, wv.y, a1);
        a2 = fmaf(xv.z, wv.z, a2);
        a3 = fmaf(xv.w, wv.w, a3);
    }
    em[gid] = bout[j] + ((a0 + a1) + (a2 + a3));
}

// ---------------------------------------------------------------- viterbi forward
__global__ __launch_bounds__(64) void viterbi_fwd(
    const float* __restrict__ em,                 // [S][NT]
    const float* __restrict__ start_trans,
    const float* __restrict__ end_trans,
    const float* __restrict__ trans,              // [NT][NT] (from,to)
    unsigned char* __restrict__ bp,               // [S][NT]
    int* __restrict__ last_out)
{
    const int j = threadIdx.x;
    const bool act = (j < NT);
    __shared__ __align__(16) float sc[2][NT];

    float tc[NT];
    if (act) {
        #pragma unroll
        for (int i = 0; i < NT; ++i) tc[i] = trans[i * NT + j];
        sc[0][j] = start_trans[j] + em[j];
        bp[j] = (unsigned char)j;
    }
    __syncthreads();

    float e_cur = act ? em[NT + j] : 0.f;
    for (int t = 1; t < S; ++t) {
        float e_nxt = (act && t + 1 < S) ? em[(size_t)(t + 1) * NT + j] : 0.f;

        const float* sp = sc[(t - 1) & 1];
        float s0[NT];
        #pragma unroll
        for (int i = 0; i < NT; i += 4) {
            float4 v = *(const float4*)(sp + i);
            s0[i] = v.x; s0[i+1] = v.y; s0[i+2] = v.z; s0[i+3] = v.w;
        }
        float bestv = s0[0] + tc[0];
        int   besti = 0;
        #pragma unroll
        for (int i = 1; i < NT; ++i) {
            float v = s0[i] + tc[i];
            if (v > bestv) { bestv = v; besti = i; }   // strict > : first-index ties
        }
        if (act) {
            sc[t & 1][j] = bestv + e_cur;
            bp[(size_t)t * NT + j] = (unsigned char)besti;
        }
        __syncthreads();
        e_cur = e_nxt;
    }

    if (j == 0) {
        const float* sp = sc[(S - 1) & 1];
        float bv = sp[0] + end_trans[0];
        int   bi = 0;
        for (int i = 1; i < NT; ++i) {
            float v = sp[i] + end_trans[i];
            if (v > bv) { bv = v; bi = i; }
        }
        *last_out = bi;
    }
}

// ---------------------------------------------------------------- backtrace
__global__ __launch_bounds__(64) void bt_maps(
    const unsigned char* __restrict__ bp, unsigned char* __restrict__ maps)
{
    __shared__ unsigned char lbp[CLEN * NT];
    const int c = blockIdx.x, tid = threadIdx.x;
    const unsigned* src = (const unsigned*)(bp + (size_t)c * CLEN * NT);
    unsigned* dst = (unsigned*)lbp;
    for (int q = tid; q < CLEN * NT / 4; q += 64) dst[q] = src[q];
    __syncthreads();
    if (tid < NT) {
        int x = tid;
        for (int t = CLEN - 1; t >= 0; --t) x = lbp[t * NT + x];
        maps[c * NT + tid] = (unsigned char)x;
    }
}

__global__ __launch_bounds__(64) void bt_boundary(
    const unsigned char* __restrict__ maps, const int* __restrict__ last_out,
    int* __restrict__ btags)
{
    __shared__ unsigned char m[NCHUNK * NT];
    const int tid = threadIdx.x;
    for (int q = tid; q < NCHUNK * NT; q += 64) m[q] = maps[q];
    __syncthreads();
    if (tid == 0) {
        int x = *last_out;
        btags[NCHUNK - 1] = x;
        for (int c = NCHUNK - 1; c >= 1; --c) {
            x = m[c * NT + x];
            btags[c - 1] = x;
        }
    }
}

__global__ __launch_bounds__(64) void bt_emit(
    const unsigned char* __restrict__ bp, const int* __restrict__ btags,
    int* __restrict__ path)
{
    __shared__ unsigned char lbp[CLEN * NT];
    const int c = blockIdx.x, tid = threadIdx.x;
    const unsigned* src = (const unsigned*)(bp + (size_t)c * CLEN * NT);
    unsigned* dst = (unsigned*)lbp;
    for (int q = tid; q < CLEN * NT / 4; q += 64) dst[q] = src[q];
    __syncthreads();
    if (tid == 0) {
        int x = btags[c];
        path[c * CLEN + CLEN - 1] = x;
        for (int t = CLEN - 1; t >= 1; --t) {
            x = lbp[t * NT + x];
            path[c * CLEN + t - 1] = x;
        }
    }
}

// ---------------------------------------------------------------- launcher
extern "C" void kernel_launch(void* const* d_in, const int* in_sizes, int n_in,
                              void* d_out, int out_size, void* d_ws, size_t ws_size,
                              hipStream_t stream) {
    const int*   sent   = (const int*)  d_in[0];
    const float* embed  = (const float*)d_in[1];
    const float* Wih_f  = (const float*)d_in[2];
    const float* Whh_f  = (const float*)d_in[3];
    const float* bih_f  = (const float*)d_in[4];
    const float* bhh_f  = (const float*)d_in[5];
    const float* Wih_b  = (const float*)d_in[6];
    const float* Whh_b  = (const float*)d_in[7];
    const float* bih_b  = (const float*)d_in[8];
    const float* bhh_b  = (const float*)d_in[9];
    const float* Wout   = (const float*)d_in[10];
    const float* bout   = (const float*)d_in[11];
    const float* start_trans = (const float*)d_in[12];
    const float* end_trans   = (const float*)d_in[13];
    const float* trans       = (const float*)d_in[14];
    int* path = (int*)d_out;

    char* ws = (char*)d_ws;
    size_t off = 0;
    float* xg = (float*)(ws + off); off += (size_t)2 * S * G * 4;   // 64 MB
    float* lo = (float*)(ws + off); off += (size_t)S * 512 * 4;     // 16 MB
    float* em = (float*)(ws + off); off += (size_t)S * NT * 4;      // 640 KB
    unsigned char* bp   = (unsigned char*)(ws + off); off += (size_t)S * NT;  // 160 KB
    unsigned char* maps = (unsigned char*)(ws + off); off += 4096;
    int* btags = (int*)(ws + off); off += 1024;
    int* lastp = (int*)(ws + off); off += 256;
    int* flags = (int*)(ws + off); off += 256;

    init_flags<<<dim3(1), 64, 0, stream>>>(flags);
    xg_project<<<dim3(S / 32, 4, 2), 256, 0, stream>>>(
        sent, embed, Wih_f, bih_f, bhh_f, Wih_b, bih_b, bhh_b, xg);
    lstm_scan_mc<<<dim3(NB, 2), 256, 0, stream>>>(xg, Whh_f, Whh_b, lo, flags);
    emissions_kernel<<<dim3((S * NT + 255) / 256), 256, 0, stream>>>(lo, Wout, bout, em);
    viterbi_fwd<<<dim3(1), 64, 0, stream>>>(em, start_trans, end_trans, trans, bp, lastp);
    bt_maps<<<dim3(NCHUNK), 64, 0, stream>>>(bp, maps);
    bt_boundary<<<dim3(1), 64, 0, stream>>>(maps, lastp, btags);
    bt_emit<<<dim3(NCHUNK), 64, 0, stream>>>(bp, btags, path);
}

// Round 3
// 17869.287 us; speedup vs baseline: 8.6796x; 2.1009x over previous
//
#include <hip/hip_runtime.h>
#include <hip/hip_bf16.h>

// BiLSTM-CRF on MI355X.  VOCAB=50000, EMB=256, HID=512 (H=256/dir), NTAG=20, SEQ=8192.
//
// Round-3 changes:
//  * lstm_scan_mc / xg_project: 512 threads, 128 weight-floats per thread
//    (half-row) -> guaranteed register-resident (no spill, no AGPR games).
//    Partial dot-products combined via LDS.
//  * Cross-CU h exchange: NO flags, NO release fences. lo[] is pre-filled
//    with a NaN bit-sentinel each launch; producers store h with relaxed
//    agent-scope (sc1 write-through to LLC); consumers poll the data words
//    until bits != sentinel (h is never NaN). One LLC round trip per step.

#define S    8192
#define E    256
#define Hh   256          // per-direction hidden
#define G    1024         // 4*Hh gates
#define NT   20
#define NB   4            // blocks (CUs) per direction
#define NCHUNK 128        // 8192 / 64
#define CLEN   64
#define SENT 0x7FC0DEADu  // NaN bit pattern; h/emission values are never NaN

// ---------------------------------------------------------------- sentinel fill
__global__ __launch_bounds__(256) void sentinel_fill(unsigned int* __restrict__ lo_u)
{
    // lo is S*512 words; 4096 blocks x 256 threads x 4 words
    size_t base = (size_t)blockIdx.x * 1024 + threadIdx.x;
    #pragma unroll
    for (int i = 0; i < 4; ++i)
        __hip_atomic_store(&lo_u[base + (size_t)i * 256], SENT,
                           __ATOMIC_RELAXED, __HIP_MEMORY_SCOPE_AGENT);
}

// ---------------------------------------------------------------- xg projection
// Block: 32 timesteps x 256 gate rows. 512 threads: half = tid>>8 owns
// k in [half*128, half*128+128); 128 weight floats in VGPRs.
__global__ __launch_bounds__(512, 2) void xg_project(
    const int* __restrict__ sent, const float* __restrict__ embed,
    const float* __restrict__ Wih_f, const float* __restrict__ bih_f, const float* __restrict__ bhh_f,
    const float* __restrict__ Wih_b, const float* __restrict__ bih_b, const float* __restrict__ bhh_b,
    float* __restrict__ xg)                       // [2][S][G]
{
    const int tb  = blockIdx.x;                   // 0..255 (32 timesteps each)
    const int rb  = blockIdx.y;                   // 0..3
    const int dir = blockIdx.z;                   // 0..1
    const int tid  = threadIdx.x;
    const int half = tid >> 8;                    // 0/1
    const int idx  = tid & 255;
    const int r    = rb * 256 + idx;              // gate row 0..1023
    const float* Wih = dir ? Wih_b : Wih_f;

    __shared__ __align__(16) float4 xs4[32 * 64]; // 32 timesteps x 256 floats (32 KB)
    __shared__ float psum[512];

    const int t0 = tb * 32;
    #pragma unroll
    for (int i = 0; i < 4; ++i) {
        int q   = i * 512 + tid;                  // 2048 float4 total
        int row = q >> 6;
        int c4  = q & 63;
        int widx = sent[t0 + row];
        xs4[q] = *(const float4*)(embed + (size_t)widx * E + (size_t)c4 * 4);
    }

    float w[128];
    #pragma unroll
    for (int k = 0; k < 128; k += 4) {
        float4 v = *(const float4*)(Wih + (size_t)r * E + half * 128 + k);
        w[k] = v.x; w[k+1] = v.y; w[k+2] = v.z; w[k+3] = v.w;
    }
    float bias = 0.f;
    if (tid < 256) bias = dir ? (bih_b[r] + bhh_b[r]) : (bih_f[r] + bhh_f[r]);
    __syncthreads();

    const float* xs = (const float*)xs4 + half * 128;
    float* outb = xg + ((size_t)dir * S + t0) * G + r;
    for (int tt = 0; tt < 32; ++tt) {
        float a0 = 0.f, a1 = 0.f, a2 = 0.f, a3 = 0.f;
        #pragma unroll
        for (int k = 0; k < 128; k += 4) {
            float4 h4 = *(const float4*)(xs + tt * E + k);   // LDS broadcast
            a0 = fmaf(w[k],   h4.x, a0);
            a1 = fmaf(w[k+1], h4.y, a1);
            a2 = fmaf(w[k+2], h4.z, a2);
            a3 = fmaf(w[k+3], h4.w, a3);
        }
        psum[tid] = (a0 + a1) + (a2 + a3);
        __syncthreads();
        if (tid < 256)
            outb[(size_t)tt * G] = bias + (psum[tid] + psum[tid + 256]);
        __syncthreads();                          // psum reused next tt
    }
}

// ---------------------------------------------------------------- LSTM scan
// Grid (NB, 2). Block (b,dir) owns h indices [b*64, b*64+64) = 256 gate rows.
// 512 threads: (half, idx) -> gate row (idx>>6)*256 + b*64 + (idx&63),
// k-range half*128..half*128+128. Whh half-row in 128 VGPRs.
__global__ __launch_bounds__(512, 2) void lstm_scan_mc(
    const float* __restrict__ xg,                 // [2][S][G]
    const float* __restrict__ Whh_f,
    const float* __restrict__ Whh_b,
    float* __restrict__ out)                      // [S][512], sentinel-prefilled
{
    const int b    = blockIdx.x;
    const int dir  = blockIdx.y;
    const int tid  = threadIdx.x;
    const int half = tid >> 8;
    const int idx  = tid & 255;
    const int gate = idx >> 6;
    const int hloc = idx & 63;
    const int hidx = b * 64 + hloc;
    const int row  = gate * Hh + hidx;
    const float* W   = dir ? Whh_b : Whh_f;
    const float* xgd = xg + (size_t)dir * S * G;

    float w[128];
    #pragma unroll
    for (int k = 0; k < 128; k += 4) {
        float4 v = *(const float4*)(W + (size_t)row * Hh + half * 128 + k);
        w[k] = v.x; w[k+1] = v.y; w[k+2] = v.z; w[k+3] = v.w;
    }

    __shared__ __align__(16) float h_lds[Hh];
    __shared__ float psum[512];
    __shared__ float gates_lds[256];
    if (tid < Hh) h_lds[tid] = 0.f;
    float c = 0.f;

    const int t0 = dir ? (S - 1) : 0;
    const int dt = dir ? -1 : 1;
    float xg_cur = (tid < 256) ? xgd[(size_t)t0 * G + row] : 0.f;
    __syncthreads();

    for (int s = 0; s < S; ++s) {
        const int t = t0 + dt * s;
        float xg_next = 0.f;
        if (tid < 256 && s + 1 < S) xg_next = xgd[(size_t)(t + dt) * G + row];

        // partial matvec over this thread's k-half (h via wave-uniform LDS bcast)
        const float* hh = h_lds + half * 128;
        float a0 = 0.f, a1 = 0.f, a2 = 0.f, a3 = 0.f;
        #pragma unroll
        for (int k = 0; k < 128; k += 4) {
            float4 h4 = *(const float4*)(hh + k);
            a0 = fmaf(w[k],   h4.x, a0);
            a1 = fmaf(w[k+1], h4.y, a1);
            a2 = fmaf(w[k+2], h4.z, a2);
            a3 = fmaf(w[k+3], h4.w, a3);
        }
        psum[tid] = (a0 + a1) + (a2 + a3);
        __syncthreads();                                     // partials ready

        if (tid < 256) {
            float acc = xg_cur + (psum[idx] + psum[idx + 256]);
            float a = (gate == 2) ? tanhf(acc) : 1.f / (1.f + expf(-acc));
            gates_lds[idx] = a;
        }
        __syncthreads();                                     // gates ready

        if (tid < 64) {                                      // wave 0: cell update
            float iv = gates_lds[hloc];
            float fv = gates_lds[64 + hloc];
            float gv = gates_lds[128 + hloc];
            float ov = gates_lds[192 + hloc];
            c = fv * c + iv * gv;
            float h = ov * tanhf(c);
            // relaxed agent-scope store: sc1 write-through to LLC, no fence
            __hip_atomic_store(out + (size_t)t * 512 + dir * Hh + hidx, h,
                               __ATOMIC_RELAXED, __HIP_MEMORY_SCOPE_AGENT);
            h_lds[hidx] = h;                                 // own segment direct
        }
        // poll peers' h words (written exactly once; never the NaN sentinel)
        if (s + 1 < S && tid < Hh && (tid >> 6) != b) {
            const unsigned int* srcp =
                (const unsigned int*)(out + (size_t)t * 512 + dir * Hh + tid);
            unsigned int v;
            do {
                v = __hip_atomic_load(srcp, __ATOMIC_RELAXED,
                                      __HIP_MEMORY_SCOPE_AGENT);
            } while (v == SENT);
            h_lds[tid] = __uint_as_float(v);
        }
        __syncthreads();                                     // h(t) complete in LDS
        xg_cur = xg_next;
    }
}

// ---------------------------------------------------------------- emissions
__global__ __launch_bounds__(256) void emissions_kernel(
    const float* __restrict__ lo,                 // [S][512]
    const float* __restrict__ Wout,               // [NT][512]
    const float* __restrict__ bout,
    float* __restrict__ em)                       // [S][NT]
{
    int gid = blockIdx.x * blockDim.x + threadIdx.x;
    if (gid >= S * NT) return;
    int t = gid / NT;
    int j = gid - t * NT;
    const float* x = lo + (size_t)t * 512;
    const float* w = Wout + (size_t)j * 512;
    float a0 = 0.f, a1 = 0.f, a2 = 0.f, a3 = 0.f;
    #pragma unroll 8
    for (int k = 0; k < 512; k += 4) {
        float4 xv = *(const float4*)(x + k);
        float4 wv = *(const float4*)(w + k);
        a0 = fmaf(xv.x, wv.x, a0);
        a1 = fmaf(xv.y, wv.y, a1);
        a2 = fmaf(xv.z, wv.z, a2);
        a3 = fmaf(xv.w, wv.w, a3);
    }
    em[gid] = bout[j] + ((a0 + a1) + (a2 + a3));
}

// ---------------------------------------------------------------- viterbi forward
__global__ __launch_bounds__(64) void viterbi_fwd(
    const float* __restrict__ em,                 // [S][NT]
    const float* __restrict__ start_trans,
    const float* __restrict__ end_trans,
    const float* __restrict__ trans,              // [NT][NT] (from,to)
    unsigned char* __restrict__ bp,               // [S][NT]
    int* __restrict__ last_out)
{
    const int j = threadIdx.x;
    const bool act = (j < NT);
    __shared__ __align__(16) float sc[2][NT];

    float tc[NT];
    if (act) {
        #pragma unroll
        for (int i = 0; i < NT; ++i) tc[i] = trans[i * NT + j];
        sc[0][j] = start_trans[j] + em[j];
        bp[j] = (unsigned char)j;
    }
    __syncthreads();

    float e_cur = act ? em[NT + j] : 0.f;
    for (int t = 1; t < S; ++t) {
        float e_nxt = (act && t + 1 < S) ? em[(size_t)(t + 1) * NT + j] : 0.f;

        const float* sp = sc[(t - 1) & 1];
        float s0[NT];
        #pragma unroll
        for (int i = 0; i < NT; i += 4) {
            float4 v = *(const float4*)(sp + i);
            s0[i] = v.x; s0[i+1] = v.y; s0[i+2] = v.z; s0[i+3] = v.w;
        }
        float bestv = s0[0] + tc[0];
        int   besti = 0;
        #pragma unroll
        for (int i = 1; i < NT; ++i) {
            float v = s0[i] + tc[i];
            if (v > bestv) { bestv = v; besti = i; }   // strict > : first-index ties
        }
        if (act) {
            sc[t & 1][j] = bestv + e_cur;
            bp[(size_t)t * NT + j] = (unsigned char)besti;
        }
        __syncthreads();
        e_cur = e_nxt;
    }

    if (j == 0) {
        const float* sp = sc[(S - 1) & 1];
        float bv = sp[0] + end_trans[0];
        int   bi = 0;
        for (int i = 1; i < NT; ++i) {
            float v = sp[i] + end_trans[i];
            if (v > bv) { bv = v; bi = i; }
        }
        *last_out = bi;
    }
}

// ---------------------------------------------------------------- backtrace
__global__ __launch_bounds__(64) void bt_maps(
    const unsigned char* __restrict__ bp, unsigned char* __restrict__ maps)
{
    __shared__ unsigned char lbp[CLEN * NT];
    const int c = blockIdx.x, tid = threadIdx.x;
    const unsigned* src = (const unsigned*)(bp + (size_t)c * CLEN * NT);
    unsigned* dst = (unsigned*)lbp;
    for (int q = tid; q < CLEN * NT / 4; q += 64) dst[q] = src[q];
    __syncthreads();
    if (tid < NT) {
        int x = tid;
        for (int t = CLEN - 1; t >= 0; --t) x = lbp[t * NT + x];
        maps[c * NT + tid] = (unsigned char)x;
    }
}

__global__ __launch_bounds__(64) void bt_boundary(
    const unsigned char* __restrict__ maps, const int* __restrict__ last_out,
    int* __restrict__ btags)
{
    __shared__ unsigned char m[NCHUNK * NT];
    const int tid = threadIdx.x;
    for (int q = tid; q < NCHUNK * NT; q += 64) m[q] = maps[q];
    __syncthreads();
    if (tid == 0) {
        int x = *last_out;
        btags[NCHUNK - 1] = x;
        for (int c = NCHUNK - 1; c >= 1; --c) {
            x = m[c * NT + x];
            btags[c - 1] = x;
        }
    }
}

__global__ __launch_bounds__(64) void bt_emit(
    const unsigned char* __restrict__ bp, const int* __restrict__ btags,
    int* __restrict__ path)
{
    __shared__ unsigned char lbp[CLEN * NT];
    const int c = blockIdx.x, tid = threadIdx.x;
    const unsigned* src = (const unsigned*)(bp + (size_t)c * CLEN * NT);
    unsigned* dst = (unsigned*)lbp;
    for (int q = tid; q < CLEN * NT / 4; q += 64) dst[q] = src[q];
    __syncthreads();
    if (tid == 0) {
        int x = btags[c];
        path[c * CLEN + CLEN - 1] = x;
        for (int t = CLEN - 1; t >= 1; --t) {
            x = lbp[t * NT + x];
            path[c * CLEN + t - 1] = x;
        }
    }
}

// ---------------------------------------------------------------- launcher
extern "C" void kernel_launch(void* const* d_in, const int* in_sizes, int n_in,
                              void* d_out, int out_size, void* d_ws, size_t ws_size,
                              hipStream_t stream) {
    const int*   sent   = (const int*)  d_in[0];
    const float* embed  = (const float*)d_in[1];
    const float* Wih_f  = (const float*)d_in[2];
    const float* Whh_f  = (const float*)d_in[3];
    const float* bih_f  = (const float*)d_in[4];
    const float* bhh_f  = (const float*)d_in[5];
    const float* Wih_b  = (const float*)d_in[6];
    const float* Whh_b  = (const float*)d_in[7];
    const float* bih_b  = (const float*)d_in[8];
    const float* bhh_b  = (const float*)d_in[9];
    const float* Wout   = (const float*)d_in[10];
    const float* bout   = (const float*)d_in[11];
    const float* start_trans = (const float*)d_in[12];
    const float* end_trans   = (const float*)d_in[13];
    const float* trans       = (const float*)d_in[14];
    int* path = (int*)d_out;

    char* ws = (char*)d_ws;
    size_t off = 0;
    float* xg = (float*)(ws + off); off += (size_t)2 * S * G * 4;   // 64 MB
    float* lo = (float*)(ws + off); off += (size_t)S * 512 * 4;     // 16 MB
    float* em = (float*)(ws + off); off += (size_t)S * NT * 4;      // 640 KB
    unsigned char* bp   = (unsigned char*)(ws + off); off += (size_t)S * NT;  // 160 KB
    unsigned char* maps = (unsigned char*)(ws + off); off += 4096;
    int* btags = (int*)(ws + off); off += 1024;
    int* lastp = (int*)(ws + off); off += 256;

    sentinel_fill<<<dim3(4096), 256, 0, stream>>>((unsigned int*)lo);
    xg_project<<<dim3(S / 32, 4, 2), 512, 0, stream>>>(
        sent, embed, Wih_f, bih_f, bhh_f, Wih_b, bih_b, bhh_b, xg);
    lstm_scan_mc<<<dim3(NB, 2), 512, 0, stream>>>(xg, Whh_f, Whh_b, lo);
    emissions_kernel<<<dim3((S * NT + 255) / 256), 256, 0, stream>>>(lo, Wout, bout, em);
    viterbi_fwd<<<dim3(1), 64, 0, stream>>>(em, start_trans, end_trans, trans, bp, lastp);
    bt_maps<<<dim3(NCHUNK), 64, 0, stream>>>(bp, maps);
    bt_boundary<<<dim3(1), 64, 0, stream>>>(maps, lastp, btags);
    bt_emit<<<dim3(NCHUNK), 64, 0, stream>>>(bp, btags, path);
}

// Round 4
// 15611.948 us; speedup vs baseline: 9.9346x; 1.1446x over previous
//
#include <hip/hip_runtime.h>
#include <hip/hip_bf16.h>

// BiLSTM-CRF on MI355X.  VOCAB=50000, EMB=256, HID=512 (H=256/dir), NTAG=20, SEQ=8192.
//
// Round-4 changes:
//  * lstm_scan_mc / xg_project: 1024 threads, 64 weight-floats per thread
//    (quarter-row). Fits the 128-VGPR budget at 4 waves/SIMD -> compiler has
//    no reason to use AGPRs (round 3: w[128] went to AGPRs, VGPR_Count=88,
//    every FMA paid an accvgpr_read).
//  * viterbi_fwd: all-64-lane in-register formulation. Lane (g,j), g=0..2,
//    computes a 7-wide partial argmax over from-tags for to-tag j; 3-way
//    combine via __shfl with first-index tie semantics; score redistribution
//    via 7 shuffles instead of LDS ping-pong + barriers.

#define S    8192
#define E    256
#define Hh   256          // per-direction hidden
#define G    1024         // 4*Hh gates
#define NT   20
#define NB   4            // blocks (CUs) per direction
#define NCHUNK 128        // 8192 / 64
#define CLEN   64
#define SENT 0x7FC0DEADu  // NaN bit pattern; h values are never NaN

// ---------------------------------------------------------------- sentinel fill
__global__ __launch_bounds__(256) void sentinel_fill(unsigned int* __restrict__ lo_u)
{
    size_t base = (size_t)blockIdx.x * 1024 + threadIdx.x;
    #pragma unroll
    for (int i = 0; i < 4; ++i)
        __hip_atomic_store(&lo_u[base + (size_t)i * 256], SENT,
                           __ATOMIC_RELAXED, __HIP_MEMORY_SCOPE_AGENT);
}

// ---------------------------------------------------------------- xg projection
// Block: 32 timesteps x 256 gate rows. 1024 threads: q = tid>>8 owns
// k in [q*64, q*64+64); 64 weight floats in VGPRs.
__global__ __launch_bounds__(1024, 4) void xg_project(
    const int* __restrict__ sent, const float* __restrict__ embed,
    const float* __restrict__ Wih_f, const float* __restrict__ bih_f, const float* __restrict__ bhh_f,
    const float* __restrict__ Wih_b, const float* __restrict__ bih_b, const float* __restrict__ bhh_b,
    float* __restrict__ xg)                       // [2][S][G]
{
    const int tb  = blockIdx.x;                   // 0..255 (32 timesteps each)
    const int rb  = blockIdx.y;                   // 0..3
    const int dir = blockIdx.z;                   // 0..1
    const int tid = threadIdx.x;
    const int q   = tid >> 8;                     // k-quarter 0..3
    const int idx = tid & 255;
    const int r   = rb * 256 + idx;               // gate row 0..1023
    const float* Wih = dir ? Wih_b : Wih_f;

    __shared__ __align__(16) float4 xs4[32 * 64]; // 32 timesteps x 256 floats (32 KB)
    __shared__ float psum[1024];

    const int t0 = tb * 32;
    #pragma unroll
    for (int i = 0; i < 2; ++i) {
        int qq  = i * 1024 + tid;                 // 2048 float4 total
        int row = qq >> 6;
        int c4  = qq & 63;
        int widx = sent[t0 + row];
        xs4[qq] = *(const float4*)(embed + (size_t)widx * E + (size_t)c4 * 4);
    }

    float w[64];
    #pragma unroll
    for (int k = 0; k < 64; k += 4) {
        float4 v = *(const float4*)(Wih + (size_t)r * E + q * 64 + k);
        w[k] = v.x; w[k+1] = v.y; w[k+2] = v.z; w[k+3] = v.w;
    }
    float bias = 0.f;
    if (tid < 256) bias = dir ? (bih_b[r] + bhh_b[r]) : (bih_f[r] + bhh_f[r]);
    __syncthreads();

    const float* xs = (const float*)xs4 + q * 64;
    float* outb = xg + ((size_t)dir * S + t0) * G + r;
    for (int tt = 0; tt < 32; ++tt) {
        float a0 = 0.f, a1 = 0.f, a2 = 0.f, a3 = 0.f;
        #pragma unroll
        for (int k = 0; k < 64; k += 4) {
            float4 h4 = *(const float4*)(xs + tt * E + k);   // LDS broadcast
            a0 = fmaf(w[k],   h4.x, a0);
            a1 = fmaf(w[k+1], h4.y, a1);
            a2 = fmaf(w[k+2], h4.z, a2);
            a3 = fmaf(w[k+3], h4.w, a3);
        }
        psum[tid] = (a0 + a1) + (a2 + a3);
        __syncthreads();
        if (tid < 256)
            outb[(size_t)tt * G] = bias +
                ((psum[idx] + psum[idx + 256]) + (psum[idx + 512] + psum[idx + 768]));
        __syncthreads();                          // psum reused next tt
    }
}

// ---------------------------------------------------------------- LSTM scan
// Grid (NB, 2). Block (b,dir) owns h [b*64, b*64+64) = 256 gate rows.
// 1024 threads: (q, idx): gate row (idx>>6)*256 + b*64 + (idx&63),
// k-range q*64..q*64+64. Whh quarter-row in 64 VGPRs.
__global__ __launch_bounds__(1024, 4) void lstm_scan_mc(
    const float* __restrict__ xg,                 // [2][S][G]
    const float* __restrict__ Whh_f,
    const float* __restrict__ Whh_b,
    float* __restrict__ out)                      // [S][512], sentinel-prefilled
{
    const int b    = blockIdx.x;
    const int dir  = blockIdx.y;
    const int tid  = threadIdx.x;
    const int q    = tid >> 8;
    const int idx  = tid & 255;
    const int gate = idx >> 6;
    const int hloc = idx & 63;
    const int hidx = b * 64 + hloc;
    const int row  = gate * Hh + hidx;
    const float* W   = dir ? Whh_b : Whh_f;
    const float* xgd = xg + (size_t)dir * S * G;

    float w[64];
    #pragma unroll
    for (int k = 0; k < 64; k += 4) {
        float4 v = *(const float4*)(W + (size_t)row * Hh + q * 64 + k);
        w[k] = v.x; w[k+1] = v.y; w[k+2] = v.z; w[k+3] = v.w;
    }

    __shared__ __align__(16) float h_lds[Hh];
    __shared__ float psum[1024];
    __shared__ float gates_lds[256];
    if (tid < Hh) h_lds[tid] = 0.f;
    float c = 0.f;

    const int t0 = dir ? (S - 1) : 0;
    const int dt = dir ? -1 : 1;
    float xg_cur = (tid < 256) ? xgd[(size_t)t0 * G + row] : 0.f;
    __syncthreads();

    for (int s = 0; s < S; ++s) {
        const int t = t0 + dt * s;
        float xg_next = 0.f;
        if (tid < 256 && s + 1 < S) xg_next = xgd[(size_t)(t + dt) * G + row];

        // partial matvec over this thread's k-quarter (wave-uniform LDS bcast)
        const float* hh = (const float*)h_lds + q * 64;
        float a0 = 0.f, a1 = 0.f, a2 = 0.f, a3 = 0.f;
        #pragma unroll
        for (int k = 0; k < 64; k += 4) {
            float4 h4 = *(const float4*)(hh + k);
            a0 = fmaf(w[k],   h4.x, a0);
            a1 = fmaf(w[k+1], h4.y, a1);
            a2 = fmaf(w[k+2], h4.z, a2);
            a3 = fmaf(w[k+3], h4.w, a3);
        }
        psum[tid] = (a0 + a1) + (a2 + a3);
        __syncthreads();                                     // partials ready

        if (tid < 256) {
            float acc = xg_cur +
                ((psum[idx] + psum[idx + 256]) + (psum[idx + 512] + psum[idx + 768]));
            float a = (gate == 2) ? tanhf(acc) : 1.f / (1.f + expf(-acc));
            gates_lds[idx] = a;
        }
        __syncthreads();                                     // gates ready

        if (tid < 64) {                                      // wave 0: cell update
            float iv = gates_lds[hloc];
            float fv = gates_lds[64 + hloc];
            float gv = gates_lds[128 + hloc];
            float ov = gates_lds[192 + hloc];
            c = fv * c + iv * gv;
            float h = ov * tanhf(c);
            __hip_atomic_store(out + (size_t)t * 512 + dir * Hh + hidx, h,
                               __ATOMIC_RELAXED, __HIP_MEMORY_SCOPE_AGENT);
            h_lds[hidx] = h;                                 // own segment direct
        }
        // poll peers' h words (written exactly once; never the NaN sentinel)
        if (s + 1 < S && tid < Hh && (tid >> 6) != b) {
            const unsigned int* srcp =
                (const unsigned int*)(out + (size_t)t * 512 + dir * Hh + tid);
            unsigned int v;
            do {
                v = __hip_atomic_load(srcp, __ATOMIC_RELAXED,
                                      __HIP_MEMORY_SCOPE_AGENT);
            } while (v == SENT);
            h_lds[tid] = __uint_as_float(v);
        }
        __syncthreads();                                     // h(t) complete in LDS
        xg_cur = xg_next;
    }
}

// ---------------------------------------------------------------- emissions
__global__ __launch_bounds__(256) void emissions_kernel(
    const float* __restrict__ lo,                 // [S][512]
    const float* __restrict__ Wout,               // [NT][512]
    const float* __restrict__ bout,
    float* __restrict__ em)                       // [S][NT]
{
    int gid = blockIdx.x * blockDim.x + threadIdx.x;
    if (gid >= S * NT) return;
    int t = gid / NT;
    int j = gid - t * NT;
    const float* x = lo + (size_t)t * 512;
    const float* w = Wout + (size_t)j * 512;
    float a0 = 0.f, a1 = 0.f, a2 = 0.f, a3 = 0.f;
    #pragma unroll 8
    for (int k = 0; k < 512; k += 4) {
        float4 xv = *(const float4*)(x + k);
        float4 wv = *(const float4*)(w + k);
        a0 = fmaf(xv.x, wv.x, a0);
        a1 = fmaf(xv.y, wv.y, a1);
        a2 = fmaf(xv.z, wv.z, a2);
        a3 = fmaf(xv.w, wv.w, a3);
    }
    em[gid] = bout[j] + ((a0 + a1) + (a2 + a3));
}

// ---------------------------------------------------------------- viterbi forward
// 64 lanes: lane = g*20 + j (g=0..2 active, lanes 60..63 spectators).
// Lane (g,j): partial first-index argmax over from-tags i in [g*7, g*7+7)
// (padded with -inf) for to-tag j; combine 3 partials via shuffles in group
// order (strict > keeps earlier group => global first-index semantics).
__global__ __launch_bounds__(64) void viterbi_fwd(
    const float* __restrict__ em,                 // [S][NT]
    const float* __restrict__ start_trans,
    const float* __restrict__ end_trans,
    const float* __restrict__ trans,              // [NT][NT] (from,to)
    unsigned char* __restrict__ bp,               // [S][NT]
    int* __restrict__ last_out)
{
    const int lane = threadIdx.x;
    const int g    = lane / 20;                   // 0,1,2 (3 = spectator)
    const int j    = lane - g * 20;               // to-tag (0..19 for g<3)
    const int i0   = g * 7;

    float tc[7];
    #pragma unroll
    for (int u = 0; u < 7; ++u) {
        int i = i0 + u;
        tc[u] = (g < 3 && i < 20) ? trans[i * NT + j] : -3.0e38f;
    }

    const int jj = (g < 3) ? j : 0;               // safe index for spectators
    float snew  = start_trans[jj] + em[jj];       // score(0)
    if (g == 0) bp[j] = (unsigned char)j;         // t=0: identity (never used)
    float e_cur = em[NT + jj];

    for (int t = 1; t < S; ++t) {
        float s_sub[7];
        #pragma unroll
        for (int u = 0; u < 7; ++u)
            s_sub[u] = __shfl(snew, i0 + u);      // sources are lanes 0..27
        float e_nxt = (t + 1 < S) ? em[(size_t)(t + 1) * NT + jj] : 0.f;

        float bv = s_sub[0] + tc[0];
        int   bi = i0;
        #pragma unroll
        for (int u = 1; u < 7; ++u) {
            float v = s_sub[u] + tc[u];
            if (v > bv) { bv = v; bi = i0 + u; }  // strict >: first-index in group
        }
        float v0 = __shfl(bv, jj), v1 = __shfl(bv, jj + 20), v2 = __shfl(bv, jj + 40);
        int   c0 = __shfl(bi, jj), c1 = __shfl(bi, jj + 20), c2 = __shfl(bi, jj + 40);
        float best = v0; int bidx = c0;
        if (v1 > best) { best = v1; bidx = c1; }
        if (v2 > best) { best = v2; bidx = c2; }
        snew = best + e_cur;
        if (g == 0) bp[(size_t)t * NT + j] = (unsigned char)bidx;
        e_cur = e_nxt;
    }

    // final: + end_trans, first-index argmax (all lanes, uniform shuffles)
    float bv = __shfl(snew, 0) + end_trans[0];
    int   bi = 0;
    #pragma unroll 1
    for (int i = 1; i < 20; ++i) {
        float v = __shfl(snew, i) + end_trans[i];
        if (v > bv) { bv = v; bi = i; }
    }
    if (lane == 0) *last_out = bi;
}

// ---------------------------------------------------------------- backtrace
__global__ __launch_bounds__(64) void bt_maps(
    const unsigned char* __restrict__ bp, unsigned char* __restrict__ maps)
{
    __shared__ unsigned char lbp[CLEN * NT];
    const int c = blockIdx.x, tid = threadIdx.x;
    const unsigned* src = (const unsigned*)(bp + (size_t)c * CLEN * NT);
    unsigned* dst = (unsigned*)lbp;
    for (int q = tid; q < CLEN * NT / 4; q += 64) dst[q] = src[q];
    __syncthreads();
    if (tid < NT) {
        int x = tid;
        for (int t = CLEN - 1; t >= 0; --t) x = lbp[t * NT + x];
        maps[c * NT + tid] = (unsigned char)x;
    }
}

__global__ __launch_bounds__(64) void bt_boundary(
    const unsigned char* __restrict__ maps, const int* __restrict__ last_out,
    int* __restrict__ btags)
{
    __shared__ unsigned char m[NCHUNK * NT];
    const int tid = threadIdx.x;
    for (int q = tid; q < NCHUNK * NT; q += 64) m[q] = maps[q];
    __syncthreads();
    if (tid == 0) {
        int x = *last_out;
        btags[NCHUNK - 1] = x;
        for (int c = NCHUNK - 1; c >= 1; --c) {
            x = m[c * NT + x];
            btags[c - 1] = x;
        }
    }
}

__global__ __launch_bounds__(64) void bt_emit(
    const unsigned char* __restrict__ bp, const int* __restrict__ btags,
    int* __restrict__ path)
{
    __shared__ unsigned char lbp[CLEN * NT];
    const int c = blockIdx.x, tid = threadIdx.x;
    const unsigned* src = (const unsigned*)(bp + (size_t)c * CLEN * NT);
    unsigned* dst = (unsigned*)lbp;
    for (int q = tid; q < CLEN * NT / 4; q += 64) dst[q] = src[q];
    __syncthreads();
    if (tid == 0) {
        int x = btags[c];
        path[c * CLEN + CLEN - 1] = x;
        for (int t = CLEN - 1; t >= 1; --t) {
            x = lbp[t * NT + x];
            path[c * CLEN + t - 1] = x;
        }
    }
}

// ---------------------------------------------------------------- launcher
extern "C" void kernel_launch(void* const* d_in, const int* in_sizes, int n_in,
                              void* d_out, int out_size, void* d_ws, size_t ws_size,
                              hipStream_t stream) {
    const int*   sent   = (const int*)  d_in[0];
    const float* embed  = (const float*)d_in[1];
    const float* Wih_f  = (const float*)d_in[2];
    const float* Whh_f  = (const float*)d_in[3];
    const float* bih_f  = (const float*)d_in[4];
    const float* bhh_f  = (const float*)d_in[5];
    const float* Wih_b  = (const float*)d_in[6];
    const float* Whh_b  = (const float*)d_in[7];
    const float* bih_b  = (const float*)d_in[8];
    const float* bhh_b  = (const float*)d_in[9];
    const float* Wout   = (const float*)d_in[10];
    const float* bout   = (const float*)d_in[11];
    const float* start_trans = (const float*)d_in[12];
    const float* end_trans   = (const float*)d_in[13];
    const float* trans       = (const float*)d_in[14];
    int* path = (int*)d_out;

    char* ws = (char*)d_ws;
    size_t off = 0;
    float* xg = (float*)(ws + off); off += (size_t)2 * S * G * 4;   // 64 MB
    float* lo = (float*)(ws + off); off += (size_t)S * 512 * 4;     // 16 MB
    float* em = (float*)(ws + off); off += (size_t)S * NT * 4;      // 640 KB
    unsigned char* bp   = (unsigned char*)(ws + off); off += (size_t)S * NT;  // 160 KB
    unsigned char* maps = (unsigned char*)(ws + off); off += 4096;
    int* btags = (int*)(ws + off); off += 1024;
    int* lastp = (int*)(ws + off); off += 256;

    sentinel_fill<<<dim3(4096), 256, 0, stream>>>((unsigned int*)lo);
    xg_project<<<dim3(S / 32, 4, 2), 1024, 0, stream>>>(
        sent, embed, Wih_f, bih_f, bhh_f, Wih_b, bih_b, bhh_b, xg);
    lstm_scan_mc<<<dim3(NB, 2), 1024, 0, stream>>>(xg, Whh_f, Whh_b, lo);
    emissions_kernel<<<dim3((S * NT + 255) / 256), 256, 0, stream>>>(lo, Wout, bout, em);
    viterbi_fwd<<<dim3(1), 64, 0, stream>>>(em, start_trans, end_trans, trans, bp, lastp);
    bt_maps<<<dim3(NCHUNK), 64, 0, stream>>>(bp, maps);
    bt_boundary<<<dim3(1), 64, 0, stream>>>(maps, lastp, btags);
    bt_emit<<<dim3(NCHUNK), 64, 0, stream>>>(bp, btags, path);
}